// Round 2
// baseline (769.158 us; speedup 1.0000x reference)
//
#include <hip/hip_runtime.h>

// MultiLabelAttention: out[b,l,h] = softmax_s(mask(W[l,:]·X[b,s,:])) · X[b,s,h]
// B=64 S=512 H=1024 L=512, fp32 in/out.
// Fused flash-style kernel: M=32 l-rows per block, S swept in 128-col steps.
// QK^T in split-bf16 (hi/lo, 3 MFMAs) for fp32-faithful scores; PV in bf16.
// R1: identical resubmit — R0 bench died to container infra, not the kernel.

typedef float  f4_t  __attribute__((ext_vector_type(4)));
typedef __bf16 bf8_t __attribute__((ext_vector_type(8)));
typedef __bf16 bf4_t __attribute__((ext_vector_type(4)));

constexpr int Sn = 512, Hn = 1024, Ln = 512;
#define NEGINF (-1e9f)

__device__ __forceinline__ void split8(f4_t a, f4_t b, bf8_t& hi, bf8_t& lo) {
#pragma unroll
  for (int i = 0; i < 4; ++i) {
    float x = a[i];
    __bf16 h = (__bf16)x;
    hi[i] = h;
    lo[i] = (__bf16)(x - (float)h);
  }
#pragma unroll
  for (int i = 0; i < 4; ++i) {
    float x = b[i];
    __bf16 h = (__bf16)x;
    hi[4 + i] = h;
    lo[4 + i] = (__bf16)(x - (float)h);
  }
}

__global__ __launch_bounds__(256, 2)
void mla_fused(const float* __restrict__ X, const int* __restrict__ AM,
               const float* __restrict__ W, float* __restrict__ Out) {
  const int bl   = blockIdx.x;
  const int b    = bl >> 4;          // 16 l-tiles per batch
  const int l0   = (bl & 15) * 32;
  const int tid  = threadIdx.x;
  const int w    = tid >> 6;         // wave 0..3
  const int lane = tid & 63;
  const int n16  = lane & 15;
  const int quad = lane >> 4;

  // LDS: P in A-frag layout [l-row][k=s-col], V^T per wave [h-col][k=s-col]
  __shared__ __bf16 fragP[32][136];        // 8.5 KB  (pad 128->136 to spread banks)
  __shared__ __bf16 fragV[4][32][136];     // 34.8 KB (wave-private 32 h-cols per hc)
  __shared__ float  red[2][4][32];         // 1 KB    (per-wave row max / row sum)

  const f4_t fzero = {0.f, 0.f, 0.f, 0.f};
  const f4_t fneg  = {NEGINF, NEGINF, NEGINF, NEGINF};

  // O accumulator: wave owns h-range [w*256, w*256+256): 2 m-tiles x 16 n-tiles
  f4_t oacc[2][16];
#pragma unroll
  for (int mt = 0; mt < 2; ++mt)
#pragma unroll
    for (int nt = 0; nt < 16; ++nt) oacc[mt][nt] = fzero;

  // Online-softmax state, replicated per lane for its rows: row = mt*16+quad*4+r
  float m_pr[2][4], l_pr[2][4];
#pragma unroll
  for (int mt = 0; mt < 2; ++mt)
#pragma unroll
    for (int r = 0; r < 4; ++r) { m_pr[mt][r] = -3e38f; l_pr[mt][r] = 0.f; }

  const float* Xb = X + (size_t)b * Sn * Hn;

  for (int step = 0; step < 4; ++step) {
    const int s0 = step * 128;

    // ---------------- GEMM1: scores[32,128], split-bf16, no LDS ----------------
    f4_t sacc[2][2];
    sacc[0][0] = fzero; sacc[0][1] = fzero; sacc[1][0] = fzero; sacc[1][1] = fzero;

    const float* q0 = W  + (size_t)(l0 + n16) * Hn + quad * 8;
    const float* q1 = q0 + 16 * Hn;
    const float* k0 = Xb + (size_t)(s0 + w * 32 + n16) * Hn + quad * 8;
    const float* k1 = k0 + 16 * Hn;

    for (int hk = 0; hk < Hn; hk += 32) {
      bf8_t qh[2], ql[2], kh[2], kl[2];
      {
        f4_t a0 = *(const f4_t*)(q0 + hk);
        f4_t a1 = *(const f4_t*)(q0 + hk + 4);
        f4_t a2 = *(const f4_t*)(q1 + hk);
        f4_t a3 = *(const f4_t*)(q1 + hk + 4);
        f4_t c0 = *(const f4_t*)(k0 + hk);
        f4_t c1 = *(const f4_t*)(k0 + hk + 4);
        f4_t c2 = *(const f4_t*)(k1 + hk);
        f4_t c3 = *(const f4_t*)(k1 + hk + 4);
        split8(a0, a1, qh[0], ql[0]);
        split8(a2, a3, qh[1], ql[1]);
        split8(c0, c1, kh[0], kl[0]);
        split8(c2, c3, kh[1], kl[1]);
      }
#pragma unroll
      for (int mt = 0; mt < 2; ++mt)
#pragma unroll
        for (int nt = 0; nt < 2; ++nt) {
          f4_t c = sacc[mt][nt];
          c = __builtin_amdgcn_mfma_f32_16x16x32_bf16(qh[mt], kh[nt], c, 0, 0, 0);
          c = __builtin_amdgcn_mfma_f32_16x16x32_bf16(qh[mt], kl[nt], c, 0, 0, 0);
          c = __builtin_amdgcn_mfma_f32_16x16x32_bf16(ql[mt], kh[nt], c, 0, 0, 0);
          sacc[mt][nt] = c;
        }
    }

    // ---------------- mask ----------------
    {
      const int* mrow = AM + b * Sn + s0 + w * 32 + n16;
      int mk0 = mrow[0];
      int mk1 = mrow[16];
      if (!mk0) { sacc[0][0] = fneg; sacc[1][0] = fneg; }
      if (!mk1) { sacc[0][1] = fneg; sacc[1][1] = fneg; }
    }

    // ---------------- online softmax (2 barriers) ----------------
    // per-wave row max (over its 32 cols: 2 n-tiles x 16 lanes)
    float rmx[2][4];
#pragma unroll
    for (int mt = 0; mt < 2; ++mt)
#pragma unroll
      for (int r = 0; r < 4; ++r) {
        float v = fmaxf(sacc[mt][0][r], sacc[mt][1][r]);
        v = fmaxf(v, __shfl_xor(v, 1));
        v = fmaxf(v, __shfl_xor(v, 2));
        v = fmaxf(v, __shfl_xor(v, 4));
        v = fmaxf(v, __shfl_xor(v, 8));
        rmx[mt][r] = v;
      }
    if (n16 == 0) {
#pragma unroll
      for (int mt = 0; mt < 2; ++mt)
#pragma unroll
        for (int r = 0; r < 4; ++r)
          red[0][w][mt * 16 + quad * 4 + r] = rmx[mt][r];
    }
    __syncthreads();  // barrier A

    float al[2][4], psum[2][4];
#pragma unroll
    for (int mt = 0; mt < 2; ++mt)
#pragma unroll
      for (int r = 0; r < 4; ++r) {
        const int row = mt * 16 + quad * 4 + r;
        float bm = fmaxf(fmaxf(red[0][0][row], red[0][1][row]),
                         fmaxf(red[0][2][row], red[0][3][row]));
        float mn = fmaxf(m_pr[mt][r], bm);
        al[mt][r] = __expf(m_pr[mt][r] - mn);
        m_pr[mt][r] = mn;
        psum[mt][r] = 0.f;
      }

    // p = exp(s - m), write P frags, accumulate local row sums
#pragma unroll
    for (int mt = 0; mt < 2; ++mt)
#pragma unroll
      for (int nt = 0; nt < 2; ++nt)
#pragma unroll
        for (int r = 0; r < 4; ++r) {
          const int row = mt * 16 + quad * 4 + r;
          float p = __expf(sacc[mt][nt][r] - m_pr[mt][r]);
          psum[mt][r] += p;
          fragP[row][w * 32 + nt * 16 + n16] = (__bf16)p;
        }

#pragma unroll
    for (int mt = 0; mt < 2; ++mt)
#pragma unroll
      for (int r = 0; r < 4; ++r) {
        float v = psum[mt][r];
        v += __shfl_xor(v, 1);
        v += __shfl_xor(v, 2);
        v += __shfl_xor(v, 4);
        v += __shfl_xor(v, 8);
        if (n16 == 0) red[1][w][mt * 16 + quad * 4 + r] = v;
      }
    __syncthreads();  // barrier B

#pragma unroll
    for (int mt = 0; mt < 2; ++mt)
#pragma unroll
      for (int r = 0; r < 4; ++r) {
        const int row = mt * 16 + quad * 4 + r;
        float bs = red[1][0][row] + red[1][1][row] + red[1][2][row] + red[1][3][row];
        l_pr[mt][r] = l_pr[mt][r] * al[mt][r] + bs;
      }
    // rescale O by alpha (per row)
#pragma unroll
    for (int mt = 0; mt < 2; ++mt)
#pragma unroll
      for (int nt = 0; nt < 16; ++nt)
#pragma unroll
        for (int r = 0; r < 4; ++r) oacc[mt][nt][r] *= al[mt][r];

    // ---------------- GEMM2: O += P[32,128] x V[128,1024] ----------------
    // wave-private V^T staging, 32 h-cols per hc chunk
    const int colg = lane & 7;   // 8 col-groups of 4 h
    const int sg   = lane >> 3;  // 0..7 row-groups of 4 s
    for (int hc = 0; hc < 8; ++hc) {
      const int h0 = w * 256 + hc * 32;
      const float* vsrc = Xb + (size_t)(s0 + sg * 4) * Hn + h0 + colg * 4;
#pragma unroll
      for (int it = 0; it < 4; ++it) {
        const float* p = vsrc + (size_t)(it * 32) * Hn;
        f4_t r0v = *(const f4_t*)(p);
        f4_t r1v = *(const f4_t*)(p + Hn);
        f4_t r2v = *(const f4_t*)(p + 2 * Hn);
        f4_t r3v = *(const f4_t*)(p + 3 * Hn);
        const int si = it * 32 + sg * 4;
#pragma unroll
        for (int c = 0; c < 4; ++c) {
          bf4_t v;
          v[0] = (__bf16)r0v[c];
          v[1] = (__bf16)r1v[c];
          v[2] = (__bf16)r2v[c];
          v[3] = (__bf16)r3v[c];
          *(bf4_t*)&fragV[w][colg * 4 + c][si] = v;  // V^T[h][s], s-contiguous
        }
      }
      // same-wave DS ops execute in order: staging writes precede these reads
#pragma unroll
      for (int kk = 0; kk < 4; ++kk) {
        bf8_t pa0 = *(const bf8_t*)&fragP[n16][kk * 32 + quad * 8];
        bf8_t pa1 = *(const bf8_t*)&fragP[16 + n16][kk * 32 + quad * 8];
#pragma unroll
        for (int ntl = 0; ntl < 2; ++ntl) {
          bf8_t vv = *(const bf8_t*)&fragV[w][ntl * 16 + n16][kk * 32 + quad * 8];
          oacc[0][hc * 2 + ntl] =
              __builtin_amdgcn_mfma_f32_16x16x32_bf16(pa0, vv, oacc[0][hc * 2 + ntl], 0, 0, 0);
          oacc[1][hc * 2 + ntl] =
              __builtin_amdgcn_mfma_f32_16x16x32_bf16(pa1, vv, oacc[1][hc * 2 + ntl], 0, 0, 0);
        }
      }
    }
    // fragP is overwritten only after next step's barrier A -> no barrier C needed
  }

  // ---------------- epilogue: O /= l, store ----------------
  float* ob = Out + ((size_t)b * Ln + l0) * Hn;
#pragma unroll
  for (int mt = 0; mt < 2; ++mt)
#pragma unroll
    for (int r = 0; r < 4; ++r) {
      const int row = mt * 16 + quad * 4 + r;
      const float inv = 1.f / l_pr[mt][r];
#pragma unroll
      for (int nt = 0; nt < 16; ++nt) {
        ob[(size_t)row * Hn + w * 256 + nt * 16 + n16] = oacc[mt][nt][r] * inv;
      }
    }
}

extern "C" void kernel_launch(void* const* d_in, const int* in_sizes, int n_in,
                              void* d_out, int out_size, void* d_ws, size_t ws_size,
                              hipStream_t stream) {
  (void)in_sizes; (void)n_in; (void)out_size; (void)d_ws; (void)ws_size;
  const float* X  = (const float*)d_in[0];   // sequence_output [64,512,1024]
  const int*   AM = (const int*)d_in[1];     // attention_mask  [64,512]
  const float* W  = (const float*)d_in[2];   // attention_weights [512,1024]
  float* Out = (float*)d_out;                // [64,512,1024]
  mla_fused<<<dim3(64 * 16), dim3(256), 0, stream>>>(X, AM, W, Out);
}